// Round 6
// baseline (341.987 us; speedup 1.0000x reference)
//
#include <hip/hip_runtime.h>
#include <math.h>
#include <stdint.h>

#define NPART 16384
#define NSTEP 40
#define DIMA  22

typedef __attribute__((ext_vector_type(8))) short short8;
typedef __attribute__((ext_vector_type(4))) float floatx4;
typedef __attribute__((ext_vector_type(4))) int   intx4;

// ---- LDS map (bytes) ----
#define AIN_B    0        // 5 tiles x 768  (quads 0..2 only; quad3 (k>=24) = zero reg)
#define AH_B     3840     // 20 (layer,mt) groups x (1024 + 1024 + 512)
#define AOUT_B   55040    // mt0 full 2560 | mt1 compressed 640 (rows 16..19 only)
#define BIN_B    58240    // 80 f32
#define BH_B     58560    // 320 f32
#define BOUT_B   59840    // 32 f32 (rows >=20 zero)
#define ACT_B    59968    // 2 groups x 680 dw: [40 feature-pairs][pitch 17]; col16 = part-pad
#define LDS_BYTES 65408
#define STAGE_DW  14992

#define U_OFF    0
#define TRAJ_OFF 160
#define OUT0_ELEMS 13434880

union V4 { intx4 i; short8 s; floatx4 f; };

__device__ __forceinline__ uint32_t bf16r(float x) {
    uint32_t u = __float_as_uint(x);
    u += 0x7FFFu + ((u >> 16) & 1u);   // RNE
    return u >> 16;
}
__device__ __forceinline__ uint32_t pk2(float a0, float a1) {
    return bf16r(a0) | (bf16r(a1) << 16);
}
__device__ __forceinline__ float fast_tanh(float x) {
    float e = __expf(2.0f * x);
    return 1.0f - 2.0f * __builtin_amdgcn_rcpf(e + 1.0f);
}

// ---- t-MLP u(t_i), fp32 ----
__global__ void prep_u(const float* __restrict__ t_arr,
                       const float* __restrict__ tw_in, const float* __restrict__ tb_in,
                       const float* __restrict__ tw_h,  const float* __restrict__ tb_h,
                       const float* __restrict__ tw_out,const float* __restrict__ tb_out,
                       float* __restrict__ uws) {
    int i = threadIdx.x;
    if (i >= NSTEP) return;
    float ti = t_arr[i];
    float h[20], h2[20];
    #pragma unroll
    for (int j = 0; j < 20; j++) {
        float v = tw_in[j] * ti + tb_in[j];
        h[j] = v > 0.f ? v : 0.f;
    }
    #pragma unroll
    for (int l = 0; l < 4; l++) {
        #pragma unroll
        for (int j = 0; j < 20; j++) {
            float a = tb_h[l * 20 + j];
            #pragma unroll
            for (int k = 0; k < 20; k++) a += tw_h[(l * 20 + j) * 20 + k] * h[k];
            h2[j] = a > 0.f ? a : 0.f;
        }
        #pragma unroll
        for (int j = 0; j < 20; j++) h[j] = h2[j];
    }
    #pragma unroll
    for (int c = 0; c < 4; c++) {
        float a = tb_out[c];
        #pragma unroll
        for (int k = 0; k < 20; k++) a += tw_out[c * 20 + k] * h[k];
        uws[i * 4 + c] = a;
    }
}

__global__ __launch_bounds__(256) void sde_mfma(
    const float* __restrict__ z,      const float* __restrict__ t_arr,
    const float* __restrict__ Tx,     const float* __restrict__ noise,
    const float* __restrict__ dw_in,  const float* __restrict__ db_in,
    const float* __restrict__ dw_h,   const float* __restrict__ db_h,
    const float* __restrict__ dw_out, const float* __restrict__ db_out,
    const float* __restrict__ uws,
    float* __restrict__ out0,         float* __restrict__ traj)
{
    __shared__ __align__(16) uint8_t lds[LDS_BYTES];
    const int tid = threadIdx.x;

    // ---- stage swizzled bf16 weight image directly global -> LDS ----
    for (int di = tid; di < STAGE_DW; di += 256) {
        uint32_t val;
        if (di < 960) {                       // AIN: 5 x 192 dw (quads 0..2, k<24)
            int mt = di / 192, r = di % 192, lane = r >> 2, w = r & 3;
            int m = mt * 16 + (lane & 15), k = (lane >> 4) * 8 + 2 * w;
            val = pk2(dw_in[m * 24 + k], dw_in[m * 24 + k + 1]);
        } else if (di < 13760) {              // AH: 20 x 640 dw
            int q = di - 960, gg = q / 640, r = q % 640;
            int layer = gg / 5, mt = gg % 5, lane, w, k;
            if (r < 512) { int kt = r >> 8, rr = r & 255; lane = rr >> 2; w = rr & 3;
                           k = kt * 32 + (lane >> 4) * 8 + 2 * w; }
            else         { int rr = r - 512; lane = rr >> 2; w = rr & 3;
                           k = 64 + (lane >> 4) * 8 + 2 * w; }
            int m = mt * 16 + (lane & 15);
            val = pk2(dw_h[layer * 6400 + m * 80 + k],
                      dw_h[layer * 6400 + m * 80 + k + 1]);
        } else if (di < 14560) {              // AOUT
            int q = di - 13760, m, k;
            if (q < 640) {                    // mt0 full
                int r = q, lane, w;
                if (r < 512) { int kt = r >> 8, rr = r & 255; lane = rr >> 2; w = rr & 3;
                               k = kt * 32 + (lane >> 4) * 8 + 2 * w; }
                else         { int rr = r - 512; lane = rr >> 2; w = rr & 3;
                               k = 64 + (lane >> 4) * 8 + 2 * w; }
                m = lane & 15;
            } else {                          // mt1 compressed: rows 16..19 only
                int r = q - 640, w = r & 3, kt, lp;
                if (r < 64)       { kt = 0; lp = r >> 2; }
                else if (r < 128) { kt = 1; lp = (r - 64) >> 2; }
                else              { kt = 2; lp = (r - 128) >> 2; }
                m = 16 + (lp & 3); k = kt * 32 + (lp >> 2) * 8 + 2 * w;
            }
            val = pk2(dw_out[m * 80 + k], dw_out[m * 80 + k + 1]);
        } else if (di < 14640) {
            val = __float_as_uint(db_in[di - 14560]);
        } else if (di < 14960) {
            val = __float_as_uint(db_h[di - 14640]);
        } else {
            int j = di - 14960;
            val = (j < 20) ? __float_as_uint(db_out[j]) : 0u;
        }
        ((uint32_t*)lds)[di] = val;
    }

    const int lane = tid & 63;
    const int n15  = lane & 15;
    const int quad = lane >> 4;
    const int wv   = __builtin_amdgcn_readfirstlane(tid >> 6);
    const int g    = wv >> 1;
    const int h    = wv & 1;          // 0: M-rows 0-47 (+out 0-15); 1: rows 48-79 (+out 16-19)
    const int n    = blockIdx.x * 32 + g * 16 + n15;
    const int mt0i = h ? 3 : 0;
    const int nmt  = h ? 2 : 3;
    const float Txb = Tx[blockIdx.x >> 1];
    const float dtv = t_arr[1] - t_arr[0];
    const float sdt = sqrtf(dtv);
    const intx4 zero4 = {0, 0, 0, 0};
    uint32_t* act = (uint32_t*)(lds + ACT_B) + g * 680;

    // state: h=0 -> y rows quad*4+r ; h=1 (quad0 lanes) -> y rows 16+r
    float yA[4] = {0.f, 0.f, 0.f, 0.f};
    if (h == 0) {
        floatx4 zv = *(const floatx4*)(z + (size_t)n * 20 + quad * 4);
        #pragma unroll
        for (int r = 0; r < 4; r++) yA[r] = zv[r];
        *(floatx4*)(out0 + (size_t)n * 20 + quad * 4) = zv;
        act[(12 + quad) * 17 + n15] = 0u;     // static zero: pairs 12..15 (features 24..31)
    } else if (quad == 0) {
        floatx4 z2 = *(const floatx4*)(z + (size_t)n * 20 + 16);
        #pragma unroll
        for (int r = 0; r < 4; r++) yA[r] = z2[r];
        *(floatx4*)(out0 + (size_t)n * 20 + 16) = z2;
        traj[n] = 0.f;
    }
    double lq = 0.0;
    float myPart = 0.f;
    __syncthreads();

    for (int i = 0; i < NSTEP; i++) {
        // ---- write input features: [y(20), u_t(4)]; pairs 12-15 static zero ----
        if (h == 0) {
            int b = (quad * 2) * 17 + n15;
            act[b]      = pk2(yA[0], yA[1]);
            act[b + 17] = pk2(yA[2], yA[3]);
        } else if (quad == 0) {
            int b = 8 * 17 + n15;
            act[b] = pk2(yA[0], yA[1]); act[b + 17] = pk2(yA[2], yA[3]);
        } else if (quad == 1) {
            float u0 = uws[i*4+0]*Txb, u1 = uws[i*4+1]*Txb;
            float u2 = uws[i*4+2]*Txb, u3 = uws[i*4+3]*Txb;
            int b = 10 * 17 + n15;
            act[b] = pk2(u0, u1); act[b + 17] = pk2(u2, u3);
        }
        __syncthreads();                       // Wb(input)
        if (h == 1 && i > 0) {                 // logqp exchange from step i-1
            float pO = __uint_as_float(act[n15 * 17 + 16]);
            lq += 0.5 * (double)(pO + myPart) * (double)dtv;
            if (quad == 0) traj[(size_t)i * NPART + n] = (float)lq;
        }
        V4 bin;
        { int b = (quad * 4) * 17 + n15;
          bin.i = (intx4){(int)act[b], (int)act[b+17], (int)act[b+34], (int)act[b+51]}; }
        __syncthreads();                       // Rb(input)

        // ---- input layer ----
        floatx4 acc[3];
        #pragma unroll
        for (int j = 0; j < 3; j++) if (j < nmt) {
            int mt = mt0i + j;
            V4 a; a.i = (quad < 3) ? *(const intx4*)(lds + AIN_B + mt * 768 + lane * 16) : zero4;
            floatx4 c = *(const floatx4*)(lds + BIN_B + (mt * 16 + quad * 4) * 4);
            acc[j] = __builtin_amdgcn_mfma_f32_16x16x32_bf16(a.s, bin.s, c, 0, 0, 0);
        }
        #pragma unroll
        for (int j = 0; j < 3; j++) if (j < nmt) {
            int b = ((mt0i + j) * 8 + quad * 2) * 17 + n15;
            act[b]      = pk2(fmaxf(acc[j][0], 0.f), fmaxf(acc[j][1], 0.f));
            act[b + 17] = pk2(fmaxf(acc[j][2], 0.f), fmaxf(acc[j][3], 0.f));
        }

        // ---- 4 hidden tanh layers ----
        #pragma unroll
        for (int l = 0; l < 4; l++) {
            __syncthreads();                   // Wb
            V4 b0, b1, b2;
            { int b = (quad * 4) * 17 + n15;
              b0.i = (intx4){(int)act[b], (int)act[b+17], (int)act[b+34], (int)act[b+51]}; }
            { int b = (16 + quad * 4) * 17 + n15;
              b1.i = (intx4){(int)act[b], (int)act[b+17], (int)act[b+34], (int)act[b+51]}; }
            if (quad < 2) {
                int b = (32 + quad * 4) * 17 + n15;
                b2.i = (intx4){(int)act[b], (int)act[b+17], (int)act[b+34], (int)act[b+51]};
            } else b2.i = zero4;
            __syncthreads();                   // Rb
            #pragma unroll
            for (int j = 0; j < 3; j++) if (j < nmt) {
                int mt = mt0i + j;
                const uint8_t* grp = lds + AH_B + (size_t)(l * 5 + mt) * 2560;
                V4 a0; a0.i = *(const intx4*)(grp + lane * 16);
                V4 a1; a1.i = *(const intx4*)(grp + 1024 + lane * 16);
                V4 a2; a2.i = (quad < 2) ? *(const intx4*)(grp + 2048 + (lane & 31) * 16) : zero4;
                floatx4 c = *(const floatx4*)(lds + BH_B + (l * 80 + mt * 16 + quad * 4) * 4);
                c = __builtin_amdgcn_mfma_f32_16x16x32_bf16(a0.s, b0.s, c, 0, 0, 0);
                c = __builtin_amdgcn_mfma_f32_16x16x32_bf16(a1.s, b1.s, c, 0, 0, 0);
                c = __builtin_amdgcn_mfma_f32_16x16x32_bf16(a2.s, b2.s, c, 0, 0, 0);
                acc[j] = c;
            }
            #pragma unroll
            for (int j = 0; j < 3; j++) if (j < nmt) {
                int b = ((mt0i + j) * 8 + quad * 2) * 17 + n15;
                act[b]      = pk2(fast_tanh(acc[j][0]), fast_tanh(acc[j][1]));
                act[b + 17] = pk2(fast_tanh(acc[j][2]), fast_tanh(acc[j][3]));
            }
        }

        // ---- output layer ----
        __syncthreads();                       // Wb(out)
        V4 b0, b1, b2;
        { int b = (quad * 4) * 17 + n15;
          b0.i = (intx4){(int)act[b], (int)act[b+17], (int)act[b+34], (int)act[b+51]}; }
        { int b = (16 + quad * 4) * 17 + n15;
          b1.i = (intx4){(int)act[b], (int)act[b+17], (int)act[b+34], (int)act[b+51]}; }
        if (quad < 2) {
            int b = (32 + quad * 4) * 17 + n15;
            b2.i = (intx4){(int)act[b], (int)act[b+17], (int)act[b+34], (int)act[b+51]};
        } else b2.i = zero4;
        __syncthreads();                       // Rb(out)
        floatx4 oacc;
        if (h == 0) {                          // rows 0-15
            const uint8_t* grp = lds + AOUT_B;
            V4 a0; a0.i = *(const intx4*)(grp + lane * 16);
            V4 a1; a1.i = *(const intx4*)(grp + 1024 + lane * 16);
            V4 a2; a2.i = (quad < 2) ? *(const intx4*)(grp + 2048 + (lane & 31) * 16) : zero4;
            floatx4 c = *(const floatx4*)(lds + BOUT_B + quad * 16);
            c = __builtin_amdgcn_mfma_f32_16x16x32_bf16(a0.s, b0.s, c, 0, 0, 0);
            c = __builtin_amdgcn_mfma_f32_16x16x32_bf16(a1.s, b1.s, c, 0, 0, 0);
            oacc = __builtin_amdgcn_mfma_f32_16x16x32_bf16(a2.s, b2.s, c, 0, 0, 0);
        } else {                               // rows 16-19 (compressed tiles)
            const uint8_t* grp = lds + AOUT_B + 2560;
            bool a4 = (n15 < 4);
            int lp = (quad * 4 + n15) * 16;
            V4 a0; a0.i = a4 ? *(const intx4*)(grp + lp) : zero4;
            V4 a1; a1.i = a4 ? *(const intx4*)(grp + 256 + lp) : zero4;
            V4 a2; a2.i = (a4 && quad < 2) ? *(const intx4*)(grp + 512 + lp) : zero4;
            floatx4 c = *(const floatx4*)(lds + BOUT_B + 64 + quad * 16);
            c = __builtin_amdgcn_mfma_f32_16x16x32_bf16(a0.s, b0.s, c, 0, 0, 0);
            c = __builtin_amdgcn_mfma_f32_16x16x32_bf16(a1.s, b1.s, c, 0, 0, 0);
            oacc = __builtin_amdgcn_mfma_f32_16x16x32_bf16(a2.s, b2.s, c, 0, 0, 0);
        }

        // ---- SDE update + logqp partials ----
        float part = 0.f;
        size_t nbase = ((size_t)i * NPART + n) * DIMA;
        size_t obase = ((size_t)(i + 1) * NPART + n) * 20;
        if (h == 0) {
            floatx4 dW = *(const floatx4*)(noise + nbase + quad * 4);
            floatx4 st;
            #pragma unroll
            for (int r = 0; r < 4; r++) {
                float o = oacc[r], y = yA[r];
                float f = o + y;                 // f = mlp - h, h = -y
                float uu = 2.f * o + 4.f * y;    // (f - h)/sigma
                part += uu * uu;
                yA[r] = y + f * dtv + (0.5f * sdt) * dW[r];
                st[r] = yA[r];
            }
            *(floatx4*)(out0 + obase + quad * 4) = st;
            part += __shfl_xor(part, 16);
            part += __shfl_xor(part, 32);
            if (quad == 0) act[n15 * 17 + 16] = __float_as_uint(part);  // pad-col exchange
        } else {
            if (quad == 0) {
                floatx4 dW = *(const floatx4*)(noise + nbase + 16);
                floatx4 st;
                #pragma unroll
                for (int r = 0; r < 4; r++) {
                    float o = oacc[r], y = yA[r];
                    float f = o + y;
                    float uu = 2.f * o + 4.f * y;
                    part += uu * uu;
                    yA[r] = y + f * dtv + (0.5f * sdt) * dW[r];
                    st[r] = yA[r];
                }
                *(floatx4*)(out0 + obase + 16) = st;
            }
            part += __shfl_xor(part, 16);
            part += __shfl_xor(part, 32);
            myPart = part;
        }
    }
    __syncthreads();                           // final logqp exchange (step 39)
    if (h == 1) {
        float pO = __uint_as_float(act[n15 * 17 + 16]);
        lq += 0.5 * (double)(pO + myPart) * (double)dtv;
        if (quad == 0) traj[(size_t)NSTEP * NPART + n] = (float)lq;
    }
}

// out1[i] = logqp trajectory at flat (t*N+n) index 41*i + 40
__global__ void gather_logqp(const float* __restrict__ traj, float* __restrict__ out1) {
    int i = blockIdx.x * 256 + threadIdx.x;
    if (i < NPART) out1[i] = traj[(size_t)41 * i + 40];
}

extern "C" void kernel_launch(void* const* d_in, const int* in_sizes, int n_in,
                              void* d_out, int out_size, void* d_ws, size_t ws_size,
                              hipStream_t stream) {
    const float* z      = (const float*)d_in[0];
    const float* t_arr  = (const float*)d_in[1];
    const float* Tx     = (const float*)d_in[2];
    const float* noise  = (const float*)d_in[3];
    const float* tw_in  = (const float*)d_in[4];
    const float* tb_in  = (const float*)d_in[5];
    const float* tw_h   = (const float*)d_in[6];
    const float* tb_h   = (const float*)d_in[7];
    const float* tw_out = (const float*)d_in[8];
    const float* tb_out = (const float*)d_in[9];
    const float* dw_in  = (const float*)d_in[10];
    const float* db_in  = (const float*)d_in[11];
    const float* dw_h   = (const float*)d_in[12];
    const float* db_h   = (const float*)d_in[13];
    const float* dw_out = (const float*)d_in[14];
    const float* db_out = (const float*)d_in[15];

    float* wsf  = (float*)d_ws;
    float* uws  = wsf + U_OFF;
    float* traj = wsf + TRAJ_OFF;
    float* out0 = (float*)d_out;
    float* out1 = out0 + OUT0_ELEMS;

    hipLaunchKernelGGL(prep_u, dim3(1), dim3(64), 0, stream,
                       t_arr, tw_in, tb_in, tw_h, tb_h, tw_out, tb_out, uws);
    hipLaunchKernelGGL(sde_mfma, dim3(512), dim3(256), 0, stream,
                       z, t_arr, Tx, noise, dw_in, db_in, dw_h, db_h,
                       dw_out, db_out, uws, out0, traj);
    hipLaunchKernelGGL(gather_logqp, dim3(64), dim3(256), 0, stream, traj, out1);
}

// Round 7
// 310.948 us; speedup vs baseline: 1.0998x; 1.0998x over previous
//
#include <hip/hip_runtime.h>
#include <math.h>
#include <stdint.h>

#define NPART 16384
#define NSTEP 40
#define DIMA  22
#define OUT0_ELEMS 13434880
#define TRAJ_OFF   160        // ws dwords (after u scratch, unused now)

typedef __attribute__((ext_vector_type(8))) short short8;
typedef __attribute__((ext_vector_type(4))) float floatx4;
typedef __attribute__((ext_vector_type(4))) int   intx4;

union V4 { intx4 i; short8 s; floatx4 f; };

__device__ __forceinline__ uint32_t bf16r(float x) {
    uint32_t u = __float_as_uint(x);
    u += 0x7FFFu + ((u >> 16) & 1u);   // RNE
    return u >> 16;
}
__device__ __forceinline__ uint32_t pk2(float a0, float a1) {
    return bf16r(a0) | (bf16r(a1) << 16);
}
__device__ __forceinline__ float fast_tanh(float x) {
    float e = __expf(2.0f * x);
    return 1.0f - 2.0f * __builtin_amdgcn_rcpf(e + 1.0f);
}

// pack 8 consecutive floats (one lane's A-fragment row-slice) into 4 bf16-pair dwords
__device__ __forceinline__ V4 load8(const float* p) {
    floatx4 v0 = *(const floatx4*)p;
    floatx4 v1 = *(const floatx4*)(p + 4);
    V4 r;
    r.i = (intx4){ (int)pk2(v0[0], v0[1]), (int)pk2(v0[2], v0[3]),
                   (int)pk2(v1[0], v1[1]), (int)pk2(v1[2], v1[3]) };
    return r;
}

// D-layout -> B-frag permutation (validated R5). Tile2: features>=80 zero.
#define BUILD_B3(B0, B1, B2, PK)                                               \
    {                                                                          \
        _Pragma("unroll")                                                      \
        for (int w = 0; w < 4; w++) {                                          \
            int s = (((w >> 1) + 2 * quad) & 3) * 16 + n15;                    \
            int a0 = __shfl((int)PK[0][w & 1], s);                             \
            int a1 = __shfl((int)PK[1][w & 1], s);                             \
            B0[w] = (quad >= 2) ? a1 : a0;                                     \
            int a2 = __shfl((int)PK[2][w & 1], s);                             \
            int a3 = __shfl((int)PK[3][w & 1], s);                             \
            B1[w] = (quad >= 2) ? a3 : a2;                                     \
            int a4 = __shfl((int)PK[4][w & 1], s);                             \
            B2[w] = (quad >= 2) ? 0 : a4;                                      \
        }                                                                      \
    }

__global__ __launch_bounds__(256, 1) void sde_mfma(
    const float* __restrict__ z,      const float* __restrict__ t_arr,
    const float* __restrict__ Tx,     const float* __restrict__ noise,
    const float* __restrict__ dw_in,  const float* __restrict__ db_in,
    const float* __restrict__ dw_h,   const float* __restrict__ db_h,
    const float* __restrict__ dw_out, const float* __restrict__ db_out,
    const float* __restrict__ tw_in,  const float* __restrict__ tb_in,
    const float* __restrict__ tw_h,   const float* __restrict__ tb_h,
    const float* __restrict__ tw_out, const float* __restrict__ tb_out,
    float* __restrict__ out0,         float* __restrict__ traj)
{
    // LDS: biases [0,432) (BIN 0 | BH 80 | BOUT 400, pads zero), u[40][4] at 432
    __shared__ float sb[592];
    const int tid = threadIdx.x;

    for (int di = tid; di < 432; di += 256) {
        float v;
        if (di < 80)       v = db_in[di];
        else if (di < 400) v = db_h[di - 80];
        else               v = (di - 400 < 20) ? db_out[di - 400] : 0.f;
        sb[di] = v;
    }
    if (tid < NSTEP) {   // t-MLP u(t_i), fp32 (folded prep_u)
        float ti = t_arr[tid];
        float hh[20], h2[20];
        #pragma unroll
        for (int j = 0; j < 20; j++) {
            float v = tw_in[j] * ti + tb_in[j];
            hh[j] = v > 0.f ? v : 0.f;
        }
        #pragma unroll
        for (int l = 0; l < 4; l++) {
            #pragma unroll
            for (int j = 0; j < 20; j++) {
                float a = tb_h[l * 20 + j];
                #pragma unroll
                for (int k = 0; k < 20; k++) a += tw_h[(l * 20 + j) * 20 + k] * hh[k];
                h2[j] = a > 0.f ? a : 0.f;
            }
            #pragma unroll
            for (int j = 0; j < 20; j++) hh[j] = h2[j];
        }
        #pragma unroll
        for (int c = 0; c < 4; c++) {
            float a = tb_out[c];
            #pragma unroll
            for (int k = 0; k < 20; k++) a += tw_out[c * 20 + k] * hh[k];
            sb[432 + tid * 4 + c] = a;
        }
    }

    const int lane = tid & 63;
    const int n15  = lane & 15;
    const int quad = lane >> 4;
    const int wv   = tid >> 6;
    const int n    = blockIdx.x * 64 + wv * 16 + n15;
    const float Txb = Tx[blockIdx.x];
    const float dtv = t_arr[1] - t_arr[0];
    const float sdt = sqrtf(dtv);
    const intx4 zero4 = {0, 0, 0, 0};

    // ---- hoist ALL weight A-fragments into registers (loop-invariant) ----
    V4 wAin[5], wAh[4][5][3], wAout[2][3];
    {
        #pragma unroll
        for (int mt = 0; mt < 5; mt++) {
            if (quad < 3) wAin[mt] = load8(dw_in + (mt * 16 + n15) * 24 + quad * 8);
            else          wAin[mt].i = zero4;          // k>=24 pad
        }
        #pragma unroll
        for (int l = 0; l < 4; l++)
            #pragma unroll
            for (int mt = 0; mt < 5; mt++) {
                const float* base = dw_h + l * 6400 + (mt * 16 + n15) * 80 + quad * 8;
                wAh[l][mt][0] = load8(base);
                wAh[l][mt][1] = load8(base + 32);
                if (quad < 2) wAh[l][mt][2] = load8(base + 64);
                else          wAh[l][mt][2].i = zero4; // k>=80 pad
            }
        #pragma unroll
        for (int mt = 0; mt < 2; mt++) {
            int m = mt * 16 + n15;
            bool mv = (m < 20);
            const float* base = dw_out + m * 80 + quad * 8;
            wAout[mt][0].i = mv ? load8(base).i      : zero4;
            wAout[mt][1].i = mv ? load8(base + 32).i : zero4;
            wAout[mt][2].i = (mv && quad < 2) ? load8(base + 64).i : zero4;
        }
    }
    __syncthreads();

    // state in D-layout: y0[r] = y[quad*4+r]; y1[r] = y[16+quad*4+r] (quad0)
    float y0[4], y1[4] = {0.f, 0.f, 0.f, 0.f};
    {
        floatx4 zv = *(const floatx4*)(z + (size_t)n * 20 + quad * 4);
        #pragma unroll
        for (int r = 0; r < 4; r++) y0[r] = zv[r];
        *(floatx4*)(out0 + (size_t)n * 20 + quad * 4) = zv;
        if (quad == 0) {
            floatx4 z2 = *(const floatx4*)(z + (size_t)n * 20 + 16);
            #pragma unroll
            for (int r = 0; r < 4; r++) y1[r] = z2[r];
            *(floatx4*)(out0 + (size_t)n * 20 + 16) = z2;
            traj[n] = 0.f;
        }
    }

    double lq = 0.0;
    for (int i = 0; i < NSTEP; i++) {
        // ---- prefetch noise for this step (latency hidden behind 6 layers) ----
        size_t nbase = ((size_t)i * NPART + n) * DIMA;
        floatx4 dW0 = *(const floatx4*)(noise + nbase + quad * 4);
        floatx4 dW1 = {0.f, 0.f, 0.f, 0.f};
        if (quad == 0) dW1 = *(const floatx4*)(noise + nbase + 16);

        floatx4 uv = *(const floatx4*)(sb + 432 + i * 4);
        float ut0 = uv[0] * Txb, ut1 = uv[1] * Txb;
        float ut2 = uv[2] * Txb, ut3 = uv[3] * Txb;

        // ---- input B-frag: x = [y(20), u_t(4), 0 x 8] ----
        uint32_t p0[2] = { pk2(y0[0], y0[1]), pk2(y0[2], y0[3]) };
        uint32_t p1[2] = { 0, 0 };
        if (quad == 0)      { p1[0] = pk2(y1[0], y1[1]); p1[1] = pk2(y1[2], y1[3]); }
        else if (quad == 1) { p1[0] = pk2(ut0, ut1);     p1[1] = pk2(ut2, ut3); }
        V4 bin;
        #pragma unroll
        for (int w = 0; w < 4; w++) {
            int s = (((w >> 1) + 2 * quad) & 3) * 16 + n15;
            int lo = __shfl((int)p0[w & 1], s);
            int hi = __shfl((int)p1[w & 1], s);
            bin.i[w] = (quad >= 2) ? hi : lo;
        }

        // ---- input layer: relu(W_in x + b) ----
        floatx4 acc[5];
        #pragma unroll
        for (int mt = 0; mt < 5; mt++) {
            floatx4 c = *(const floatx4*)(sb + mt * 16 + quad * 4);
            acc[mt] = __builtin_amdgcn_mfma_f32_16x16x32_bf16(wAin[mt].s, bin.s, c, 0, 0, 0);
        }
        uint32_t pkA[5][2];
        #pragma unroll
        for (int mt = 0; mt < 5; mt++) {
            pkA[mt][0] = pk2(fmaxf(acc[mt][0], 0.f), fmaxf(acc[mt][1], 0.f));
            pkA[mt][1] = pk2(fmaxf(acc[mt][2], 0.f), fmaxf(acc[mt][3], 0.f));
        }

        // ---- 4 hidden tanh layers ----
        #pragma unroll
        for (int l = 0; l < 4; l++) {
            int B0[4], B1[4], B2[4];
            BUILD_B3(B0, B1, B2, pkA);
            V4 b0, b1, b2;
            b0.i = (intx4){B0[0], B0[1], B0[2], B0[3]};
            b1.i = (intx4){B1[0], B1[1], B1[2], B1[3]};
            b2.i = (intx4){B2[0], B2[1], B2[2], B2[3]};
            #pragma unroll
            for (int mt = 0; mt < 5; mt++) {
                floatx4 c = *(const floatx4*)(sb + 80 + l * 80 + mt * 16 + quad * 4);
                c = __builtin_amdgcn_mfma_f32_16x16x32_bf16(wAh[l][mt][0].s, b0.s, c, 0, 0, 0);
                c = __builtin_amdgcn_mfma_f32_16x16x32_bf16(wAh[l][mt][1].s, b1.s, c, 0, 0, 0);
                c = __builtin_amdgcn_mfma_f32_16x16x32_bf16(wAh[l][mt][2].s, b2.s, c, 0, 0, 0);
                acc[mt] = c;
            }
            #pragma unroll
            for (int mt = 0; mt < 5; mt++) {
                pkA[mt][0] = pk2(fast_tanh(acc[mt][0]), fast_tanh(acc[mt][1]));
                pkA[mt][1] = pk2(fast_tanh(acc[mt][2]), fast_tanh(acc[mt][3]));
            }
        }

        // ---- output layer (M=20 padded to 32) ----
        int B0[4], B1[4], B2[4];
        BUILD_B3(B0, B1, B2, pkA);
        V4 b0, b1, b2;
        b0.i = (intx4){B0[0], B0[1], B0[2], B0[3]};
        b1.i = (intx4){B1[0], B1[1], B1[2], B1[3]};
        b2.i = (intx4){B2[0], B2[1], B2[2], B2[3]};
        floatx4 oacc[2];
        #pragma unroll
        for (int mt = 0; mt < 2; mt++) {
            floatx4 c = *(const floatx4*)(sb + 400 + mt * 16 + quad * 4);
            c = __builtin_amdgcn_mfma_f32_16x16x32_bf16(wAout[mt][0].s, b0.s, c, 0, 0, 0);
            c = __builtin_amdgcn_mfma_f32_16x16x32_bf16(wAout[mt][1].s, b1.s, c, 0, 0, 0);
            oacc[mt] = __builtin_amdgcn_mfma_f32_16x16x32_bf16(wAout[mt][2].s, b2.s, c, 0, 0, 0);
        }

        // ---- SDE update + logqp ----
        float part = 0.f;
        size_t obase = ((size_t)(i + 1) * NPART + n) * 20;
        floatx4 st;
        #pragma unroll
        for (int r = 0; r < 4; r++) {
            float o = oacc[0][r];
            float y = y0[r];
            float f = o + y;                 // f = mlp - h, h = -y
            float uu = 2.f * o + 4.f * y;    // (f - h)/sigma
            part += uu * uu;
            y0[r] = y + f * dtv + (0.5f * sdt) * dW0[r];
            st[r] = y0[r];
        }
        *(floatx4*)(out0 + obase + quad * 4) = st;
        if (quad == 0) {
            floatx4 st2;
            #pragma unroll
            for (int r = 0; r < 4; r++) {
                float o = oacc[1][r];
                float y = y1[r];
                float f = o + y;
                float uu = 2.f * o + 4.f * y;
                part += uu * uu;
                y1[r] = y + f * dtv + (0.5f * sdt) * dW1[r];
                st2[r] = y1[r];
            }
            *(floatx4*)(out0 + obase + 16) = st2;
        }
        part += __shfl_xor(part, 16);
        part += __shfl_xor(part, 32);
        lq += 0.5 * (double)part * (double)dtv;
        if (quad == 0) traj[(size_t)(i + 1) * NPART + n] = (float)lq;
    }
}

// out1[i] = logqp trajectory at flat (t*N+n) index 41*i + 40
__global__ void gather_logqp(const float* __restrict__ traj, float* __restrict__ out1) {
    int i = blockIdx.x * 256 + threadIdx.x;
    if (i < NPART) out1[i] = traj[(size_t)41 * i + 40];
}

extern "C" void kernel_launch(void* const* d_in, const int* in_sizes, int n_in,
                              void* d_out, int out_size, void* d_ws, size_t ws_size,
                              hipStream_t stream) {
    const float* z      = (const float*)d_in[0];
    const float* t_arr  = (const float*)d_in[1];
    const float* Tx     = (const float*)d_in[2];
    const float* noise  = (const float*)d_in[3];
    const float* tw_in  = (const float*)d_in[4];
    const float* tb_in  = (const float*)d_in[5];
    const float* tw_h   = (const float*)d_in[6];
    const float* tb_h   = (const float*)d_in[7];
    const float* tw_out = (const float*)d_in[8];
    const float* tb_out = (const float*)d_in[9];
    const float* dw_in  = (const float*)d_in[10];
    const float* db_in  = (const float*)d_in[11];
    const float* dw_h   = (const float*)d_in[12];
    const float* db_h   = (const float*)d_in[13];
    const float* dw_out = (const float*)d_in[14];
    const float* db_out = (const float*)d_in[15];

    float* wsf  = (float*)d_ws;
    float* traj = wsf + TRAJ_OFF;
    float* out0 = (float*)d_out;
    float* out1 = out0 + OUT0_ELEMS;

    hipLaunchKernelGGL(sde_mfma, dim3(256), dim3(256), 0, stream,
                       z, t_arr, Tx, noise, dw_in, db_in, dw_h, db_h,
                       dw_out, db_out, tw_in, tb_in, tw_h, tb_h, tw_out, tb_out,
                       out0, traj);
    hipLaunchKernelGGL(gather_logqp, dim3(64), dim3(256), 0, stream, traj, out1);
}

// Round 8
// 274.782 us; speedup vs baseline: 1.2446x; 1.1316x over previous
//
#include <hip/hip_runtime.h>
#include <math.h>
#include <stdint.h>

#define NPART 16384
#define NSTEP 40
#define DIMA  22
#define OUT0_ELEMS 13434880
#define TRAJ_OFF   160

typedef __attribute__((ext_vector_type(8))) short short8;
typedef __attribute__((ext_vector_type(4))) float floatx4;
typedef __attribute__((ext_vector_type(4))) int   intx4;
typedef __attribute__((ext_vector_type(2))) int   intx2;

union V4 { intx4 i; short8 s; floatx4 f; };

// ---- LDS map (bytes): permuted-weight image ----
// AIN: 5 tiles x 1024
// AH:  20 (l,mt) groups x (1024 + 1024 + 512 half-tile kt2)
// AOUT:2 groups x 2560
// u-table: 160 f32
#define AIN_B   0
#define AH_B    5120
#define AOUT_B  56320
#define U_B     61440
#define LDS_BYTES 62080
#define STAGE_DW  15360

__device__ __forceinline__ uint32_t bf16r(float x) {
    uint32_t u = __float_as_uint(x);
    u += 0x7FFFu + ((u >> 16) & 1u);   // RNE
    return u >> 16;
}
__device__ __forceinline__ uint32_t pk2(float a0, float a1) {
    return bf16r(a0) | (bf16r(a1) << 16);
}
__device__ __forceinline__ float fast_tanh(float x) {
    float e = __expf(2.0f * x);
    return 1.0f - 2.0f * __builtin_amdgcn_rcpf(e + 1.0f);
}

__global__ __launch_bounds__(256, 1) void sde_mfma(
    const float* __restrict__ z,      const float* __restrict__ t_arr,
    const float* __restrict__ Tx,     const float* __restrict__ noise,
    const float* __restrict__ dw_in,  const float* __restrict__ db_in,
    const float* __restrict__ dw_h,   const float* __restrict__ db_h,
    const float* __restrict__ dw_out, const float* __restrict__ db_out,
    const float* __restrict__ tw_in,  const float* __restrict__ tb_in,
    const float* __restrict__ tw_h,   const float* __restrict__ tb_h,
    const float* __restrict__ tw_out, const float* __restrict__ tb_out,
    float* __restrict__ out0,         float* __restrict__ traj)
{
    __shared__ __align__(16) uint8_t lds[LDS_BYTES];
    const int tid = threadIdx.x;

    // ---- stage PERMUTED bf16 weight image global -> LDS ----
    // Column permutation folds the D-layout -> B-layout transform into weights:
    //   A'[m][32kt+8q+2w+jj] = A[m][16(2kt+(w>>1)) + 4q + 2(w&1) + jj]
    for (int di = tid; di < STAGE_DW; di += 256) {
        uint32_t val = 0u;
        if (di < 1280) {                       // AIN: x = [y(20), u_t(4)]
            int r = di & 255, lane = r >> 2, w = r & 3;
            int m = lane & 15, q = lane >> 4, mt = di >> 8;
            int f = -1;
            if (w < 2)            f = 4 * q + 2 * w;
            else if (q == 0)      f = 16 + 2 * (w - 2);
            else if (q == 1)      f = 20 + 2 * (w - 2);
            if (f >= 0) val = pk2(dw_in[(mt * 16 + m) * 24 + f],
                                  dw_in[(mt * 16 + m) * 24 + f + 1]);
        } else if (di < 14080) {               // AH: 20 groups x 640 dw
            int q2 = di - 1280, g = q2 / 640, r = q2 % 640;
            int l = g / 5, mt = g % 5;
            int lane, f;
            if (r < 512) {
                int kt = r >> 8, rr = r & 255, w = rr & 3;
                lane = rr >> 2;
                f = 16 * (2 * kt + (w >> 1)) + 4 * (lane >> 4) + 2 * (w & 1);
            } else {
                int rr = r - 512, d = rr & 1;
                lane = rr >> 1;
                f = 64 + 4 * (lane >> 4) + 2 * d;
            }
            int m = lane & 15;
            val = pk2(dw_h[l * 6400 + (mt * 16 + m) * 80 + f],
                      dw_h[l * 6400 + (mt * 16 + m) * 80 + f + 1]);
        } else {                               // AOUT: 2 groups x 640 dw
            int q2 = di - 14080, mt = q2 / 640, r = q2 % 640;
            int lane, f;
            if (r < 512) {
                int kt = r >> 8, rr = r & 255, w = rr & 3;
                lane = rr >> 2;
                f = 16 * (2 * kt + (w >> 1)) + 4 * (lane >> 4) + 2 * (w & 1);
            } else {
                int rr = r - 512, d = rr & 1;
                lane = rr >> 1;
                f = 64 + 4 * (lane >> 4) + 2 * d;
            }
            int m = mt * 16 + (lane & 15);
            if (m < 20) val = pk2(dw_out[m * 80 + f], dw_out[m * 80 + f + 1]);
        }
        ((uint32_t*)lds)[di] = val;
    }
    if (tid < NSTEP) {   // t-MLP u(t_i), fp32
        float ti = t_arr[tid];
        float hh[20], h2[20];
        #pragma unroll
        for (int j = 0; j < 20; j++) {
            float v = tw_in[j] * ti + tb_in[j];
            hh[j] = v > 0.f ? v : 0.f;
        }
        #pragma unroll
        for (int l = 0; l < 4; l++) {
            #pragma unroll
            for (int j = 0; j < 20; j++) {
                float a = tb_h[l * 20 + j];
                #pragma unroll
                for (int k = 0; k < 20; k++) a += tw_h[(l * 20 + j) * 20 + k] * hh[k];
                h2[j] = a > 0.f ? a : 0.f;
            }
            #pragma unroll
            for (int j = 0; j < 20; j++) hh[j] = h2[j];
        }
        #pragma unroll
        for (int c = 0; c < 4; c++) {
            float a = tb_out[c];
            #pragma unroll
            for (int k = 0; k < 20; k++) a += tw_out[c * 20 + k] * hh[k];
            ((float*)(lds + U_B))[tid * 4 + c] = a;
        }
    }

    const int lane = tid & 63;
    const int n15  = lane & 15;
    const int quad = lane >> 4;
    const int wv   = tid >> 6;
    const int n    = blockIdx.x * 64 + wv * 16 + n15;
    const float Txb = Tx[blockIdx.x];
    const float dtv = t_arr[1] - t_arr[0];
    const float sdt = sqrtf(dtv);

    // ---- hoist biases into registers (per-lane D-layout rows) ----
    floatx4 cIn[5], cH[4][5], cOut[2];
    #pragma unroll
    for (int mt = 0; mt < 5; mt++)
        cIn[mt] = *(const floatx4*)(db_in + mt * 16 + quad * 4);
    #pragma unroll
    for (int l = 0; l < 4; l++)
        #pragma unroll
        for (int mt = 0; mt < 5; mt++)
            cH[l][mt] = *(const floatx4*)(db_h + l * 80 + mt * 16 + quad * 4);
    cOut[0] = *(const floatx4*)(db_out + quad * 4);
    cOut[1] = (quad == 0) ? *(const floatx4*)(db_out + 16)
                          : (floatx4){0.f, 0.f, 0.f, 0.f};
    __syncthreads();

    // state in D-layout: y0[r] = y[quad*4+r]; y1[r] = y[16+quad*4+r] (quad0)
    float y0[4], y1[4] = {0.f, 0.f, 0.f, 0.f};
    {
        floatx4 zv = *(const floatx4*)(z + (size_t)n * 20 + quad * 4);
        #pragma unroll
        for (int r = 0; r < 4; r++) y0[r] = zv[r];
        *(floatx4*)(out0 + (size_t)n * 20 + quad * 4) = zv;
        if (quad == 0) {
            floatx4 z2 = *(const floatx4*)(z + (size_t)n * 20 + 16);
            #pragma unroll
            for (int r = 0; r < 4; r++) y1[r] = z2[r];
            *(floatx4*)(out0 + (size_t)n * 20 + 16) = z2;
            traj[n] = 0.f;
        }
    }

    double lq = 0.0;
    for (int i = 0; i < NSTEP; i++) {
        // prefetch noise (consumed at step bottom)
        size_t nbase = ((size_t)i * NPART + n) * DIMA;
        floatx4 dW0 = *(const floatx4*)(noise + nbase + quad * 4);
        floatx4 dW1 = {0.f, 0.f, 0.f, 0.f};
        if (quad == 0) dW1 = *(const floatx4*)(noise + nbase + 16);

        const float* su = (const float*)(lds + U_B) + i * 4;
        float ut0 = su[0] * Txb, ut1 = su[1] * Txb;
        float ut2 = su[2] * Txb, ut3 = su[3] * Txb;

        // ---- input B-frag: direct register pack, NO cross-lane ops ----
        V4 bin;
        bin.i[0] = pk2(y0[0], y0[1]);
        bin.i[1] = pk2(y0[2], y0[3]);
        if (quad == 0)      { bin.i[2] = pk2(y1[0], y1[1]); bin.i[3] = pk2(y1[2], y1[3]); }
        else if (quad == 1) { bin.i[2] = pk2(ut0, ut1);     bin.i[3] = pk2(ut2, ut3); }
        else                { bin.i[2] = 0;                 bin.i[3] = 0; }

        // ---- input layer: relu(W_in' x + b) ----
        floatx4 acc[5];
        #pragma unroll
        for (int mt = 0; mt < 5; mt++) {
            V4 a; a.i = *(const intx4*)(lds + AIN_B + mt * 1024 + lane * 16);
            acc[mt] = __builtin_amdgcn_mfma_f32_16x16x32_bf16(a.s, bin.s, cIn[mt], 0, 0, 0);
        }
        uint32_t pkA[5][2];
        #pragma unroll
        for (int mt = 0; mt < 5; mt++) {
            pkA[mt][0] = pk2(fmaxf(acc[mt][0], 0.f), fmaxf(acc[mt][1], 0.f));
            pkA[mt][1] = pk2(fmaxf(acc[mt][2], 0.f), fmaxf(acc[mt][3], 0.f));
        }

        // ---- 4 hidden tanh layers: B-frags are pure register renames ----
        #pragma unroll
        for (int l = 0; l < 4; l++) {
            V4 b0, b1, b2;
            b0.i = (intx4){(int)pkA[0][0], (int)pkA[0][1], (int)pkA[1][0], (int)pkA[1][1]};
            b1.i = (intx4){(int)pkA[2][0], (int)pkA[2][1], (int)pkA[3][0], (int)pkA[3][1]};
            b2.i = (intx4){(int)pkA[4][0], (int)pkA[4][1], 0, 0};
            #pragma unroll
            for (int mt = 0; mt < 5; mt++) {
                const uint8_t* grp = lds + AH_B + (size_t)(l * 5 + mt) * 2560;
                V4 a0; a0.i = *(const intx4*)(grp + lane * 16);
                V4 a1; a1.i = *(const intx4*)(grp + 1024 + lane * 16);
                intx2 h2 = *(const intx2*)(grp + 2048 + lane * 8);
                V4 a2; a2.i = (intx4){h2[0], h2[1], 0, 0};
                floatx4 c = cH[l][mt];
                c = __builtin_amdgcn_mfma_f32_16x16x32_bf16(a0.s, b0.s, c, 0, 0, 0);
                c = __builtin_amdgcn_mfma_f32_16x16x32_bf16(a1.s, b1.s, c, 0, 0, 0);
                c = __builtin_amdgcn_mfma_f32_16x16x32_bf16(a2.s, b2.s, c, 0, 0, 0);
                acc[mt] = c;
            }
            #pragma unroll
            for (int mt = 0; mt < 5; mt++) {
                pkA[mt][0] = pk2(fast_tanh(acc[mt][0]), fast_tanh(acc[mt][1]));
                pkA[mt][1] = pk2(fast_tanh(acc[mt][2]), fast_tanh(acc[mt][3]));
            }
        }

        // ---- output layer (M=20 padded to 32) ----
        V4 b0, b1, b2;
        b0.i = (intx4){(int)pkA[0][0], (int)pkA[0][1], (int)pkA[1][0], (int)pkA[1][1]};
        b1.i = (intx4){(int)pkA[2][0], (int)pkA[2][1], (int)pkA[3][0], (int)pkA[3][1]};
        b2.i = (intx4){(int)pkA[4][0], (int)pkA[4][1], 0, 0};
        floatx4 oacc[2];
        #pragma unroll
        for (int mt = 0; mt < 2; mt++) {
            const uint8_t* grp = lds + AOUT_B + (size_t)mt * 2560;
            V4 a0; a0.i = *(const intx4*)(grp + lane * 16);
            V4 a1; a1.i = *(const intx4*)(grp + 1024 + lane * 16);
            intx2 h2 = *(const intx2*)(grp + 2048 + lane * 8);
            V4 a2; a2.i = (intx4){h2[0], h2[1], 0, 0};
            floatx4 c = cOut[mt];
            c = __builtin_amdgcn_mfma_f32_16x16x32_bf16(a0.s, b0.s, c, 0, 0, 0);
            c = __builtin_amdgcn_mfma_f32_16x16x32_bf16(a1.s, b1.s, c, 0, 0, 0);
            oacc[mt] = __builtin_amdgcn_mfma_f32_16x16x32_bf16(a2.s, b2.s, c, 0, 0, 0);
        }

        // ---- SDE update + logqp ----
        float part = 0.f;
        size_t obase = ((size_t)(i + 1) * NPART + n) * 20;
        floatx4 st;
        #pragma unroll
        for (int r = 0; r < 4; r++) {
            float o = oacc[0][r];
            float y = y0[r];
            float f = o + y;                 // f = mlp - h, h = -y
            float uu = 2.f * o + 4.f * y;    // (f - h)/sigma
            part += uu * uu;
            y0[r] = y + f * dtv + (0.5f * sdt) * dW0[r];
            st[r] = y0[r];
        }
        *(floatx4*)(out0 + obase + quad * 4) = st;
        if (quad == 0) {
            floatx4 st2;
            #pragma unroll
            for (int r = 0; r < 4; r++) {
                float o = oacc[1][r];
                float y = y1[r];
                float f = o + y;
                float uu = 2.f * o + 4.f * y;
                part += uu * uu;
                y1[r] = y + f * dtv + (0.5f * sdt) * dW1[r];
                st2[r] = y1[r];
            }
            *(floatx4*)(out0 + obase + 16) = st2;
        }
        part += __shfl_xor(part, 16);
        part += __shfl_xor(part, 32);
        lq += 0.5 * (double)part * (double)dtv;
        if (quad == 0) traj[(size_t)(i + 1) * NPART + n] = (float)lq;
    }
}

// out1[i] = logqp trajectory at flat (t*N+n) index 41*i + 40
__global__ void gather_logqp(const float* __restrict__ traj, float* __restrict__ out1) {
    int i = blockIdx.x * 256 + threadIdx.x;
    if (i < NPART) out1[i] = traj[(size_t)41 * i + 40];
}

extern "C" void kernel_launch(void* const* d_in, const int* in_sizes, int n_in,
                              void* d_out, int out_size, void* d_ws, size_t ws_size,
                              hipStream_t stream) {
    const float* z      = (const float*)d_in[0];
    const float* t_arr  = (const float*)d_in[1];
    const float* Tx     = (const float*)d_in[2];
    const float* noise  = (const float*)d_in[3];
    const float* tw_in  = (const float*)d_in[4];
    const float* tb_in  = (const float*)d_in[5];
    const float* tw_h   = (const float*)d_in[6];
    const float* tb_h   = (const float*)d_in[7];
    const float* tw_out = (const float*)d_in[8];
    const float* tb_out = (const float*)d_in[9];
    const float* dw_in  = (const float*)d_in[10];
    const float* db_in  = (const float*)d_in[11];
    const float* dw_h   = (const float*)d_in[12];
    const float* db_h   = (const float*)d_in[13];
    const float* dw_out = (const float*)d_in[14];
    const float* db_out = (const float*)d_in[15];

    float* wsf  = (float*)d_ws;
    float* traj = wsf + TRAJ_OFF;
    float* out0 = (float*)d_out;
    float* out1 = out0 + OUT0_ELEMS;

    hipLaunchKernelGGL(sde_mfma, dim3(256), dim3(256), 0, stream,
                       z, t_arr, Tx, noise, dw_in, db_in, dw_h, db_h,
                       dw_out, db_out, tw_in, tb_in, tw_h, tb_h, tw_out, tb_out,
                       out0, traj);
    hipLaunchKernelGGL(gather_logqp, dim3(64), dim3(256), 0, stream, traj, out1);
}